// Round 5
// baseline (886.520 us; speedup 1.0000x reference)
//
#include <hip/hip_runtime.h>

// mLSTM block, bf16-MFMA, R5: WEIGHT COMPOSITION. Everything between LN1 and
// the gate nonlinearities is linear, so the seven pre-activation tensors
// (q,k,v,i,f,o,x_adj) are x_norm @ Weff + beff with
//   W_comb = W_up @ W_adj            (k-gate 1/8 folded into slab 1)
//   Weff[g] = W_comb @ W_g  (g=0..5), Weff[6] = W_comb
// computed on-device per launch (~17 GFLOP of weight-prep GEMMs).
// Pipeline:
//   ln1 -> xn bf16
//   prep: convT weights, compose Wbig[7168,1024] bf16 + beff[7168] f32
//   gemm_seven: xn @ Wbig -> gate math -> ht bf16, sadj=sigmoid(x_adj) bf16
//   ln2: y = LN(ht)*sadj
//   gemm_bt<1>: out = y @ Wdn + bdn + x  (f32)
//
// LDS XOR-swizzle (R4, verified conflict-free): chunk c of a 64 B row r is
// stored at slot c ^ ((r>>1)&3); staging swizzles the SOURCE address since
// global_load_lds forces dest = base + lane*16.
//
// Workspace (MiB): xn[0,32) ht[32,64) sadj[64,96) y=ht alias
//   Wbig[96,110) W_comb[110,112) WupB[112,116) WadjT[116,120)
//   WgTcat[120,132) WdnT[132,134) beff@134 (28KB). Total <135 MiB.

typedef unsigned short u16;
typedef __attribute__((ext_vector_type(4))) unsigned short u16x4;
typedef __attribute__((ext_vector_type(8))) __bf16 bf16x8;
typedef __attribute__((ext_vector_type(4))) float f32x4;

__device__ __forceinline__ float bf2f(u16 u) {
    union { unsigned int i; float f; } c; c.i = ((unsigned int)u) << 16; return c.f;
}
__device__ __forceinline__ u16 f2bf(float f) {
    union { float f; unsigned int i; } c; c.f = f;
    unsigned int lsb = (c.i >> 16) & 1u;
    c.i += 0x7fffu + lsb;                 // round-to-nearest-even
    return (u16)(c.i >> 16);
}
__device__ __forceinline__ float sigmoidf(float z) {
    return 1.0f / (1.0f + __expf(-z));
}

#define GLDS16(gp, lp)                                                        \
    __builtin_amdgcn_global_load_lds(                                         \
        (__attribute__((address_space(1))) void*)(void*)(gp),                 \
        (__attribute__((address_space(3))) void*)(lp), 16, 0, 0)

#define BM 128
#define BN 128
#define BK 32

// C[M,N] = A[M,K] @ B[K,N], Bt = B^T stored [N,K], bf16 in, fp32 acc.
// MODE 1: out f32  = (acc + bias[n]) * scale + resid[m*N+n]
// MODE 2: out bf16 normal [M,N]; out2 bf16 transposed [N,M] (no bias)
// MODE 3: out bf16 transposed only, out[n*M + m]; slab n>>10==1 scaled 1/8
template <int MODE>
__global__ __launch_bounds__(256) void gemm_bt(
    const u16* __restrict__ A, const u16* __restrict__ Bt,
    const float* __restrict__ bias, const float* __restrict__ resid,
    void* __restrict__ out, void* __restrict__ out2,
    int M, int N, int K, float scale)
{
    __shared__ __align__(16) u16 As[BM * BK];
    __shared__ __align__(16) u16 Bs[BN * BK];

    const int tid  = threadIdx.x;
    const int lane = tid & 63;
    const int wave = tid >> 6;
    const int l15  = lane & 15;
    const int quad = lane >> 4;

    const long bm = (long)blockIdx.y * BM;
    const long bn = (long)blockIdx.x * BN;
    const int  wm = (wave >> 1) * 64;
    const int  wn = (wave & 1) * 64;

    f32x4 acc[4][4] = {};

    const int  r0 = tid >> 2;
    const int  ck = (((tid & 3) ^ ((tid >> 3) & 3)) * 8);  // swizzled source chunk
    const u16* ga0 = A  + (bm + r0) * (long)K + ck;
    const u16* gb0 = Bt + (bn + r0) * (long)K + ck;
    u16* lA = &As[(wave * 64) * 8];
    u16* lB = &Bs[(wave * 64) * 8];

    const int q8s = (quad ^ ((l15 >> 1) & 3)) * 8;

    for (int k0 = 0; k0 < K; k0 += BK) {
        GLDS16(ga0 + k0, lA);
        GLDS16(ga0 + k0 + 64 * (long)K, lA + 256 * 8);
        GLDS16(gb0 + k0, lB);
        GLDS16(gb0 + k0 + 64 * (long)K, lB + 256 * 8);
        __syncthreads();

        bf16x8 af[4], bfr[4];
#pragma unroll
        for (int t = 0; t < 4; ++t) {
            af[t]  = *(const bf16x8*)&As[(wm + t * 16 + l15) * BK + q8s];
            bfr[t] = *(const bf16x8*)&Bs[(wn + t * 16 + l15) * BK + q8s];
        }
#pragma unroll
        for (int mt = 0; mt < 4; ++mt)
#pragma unroll
            for (int nt = 0; nt < 4; ++nt)
                acc[mt][nt] = __builtin_amdgcn_mfma_f32_16x16x32_bf16(
                    af[mt], bfr[nt], acc[mt][nt], 0, 0, 0);
        __syncthreads();
    }

    // C/D layout: col = lane&15, row = quad*4 + reg
#pragma unroll
    for (int nt = 0; nt < 4; ++nt) {
        const long n  = bn + wn + nt * 16 + l15;
        const float bv = (MODE == 1) ? bias[n] : 0.0f;
        const float sc = (MODE == 3) ? (((n >> 10) == 1) ? 0.125f : 1.0f) : scale;
#pragma unroll
        for (int mt = 0; mt < 4; ++mt) {
            const long m0 = bm + wm + mt * 16 + quad * 4;
            if (MODE == 1) {
#pragma unroll
                for (int r = 0; r < 4; ++r) {
                    const long idx = (m0 + r) * N + n;
                    ((float*)out)[idx] = (acc[mt][nt][r] + bv) * sc + resid[idx];
                }
            } else {
                u16x4 w;
#pragma unroll
                for (int r = 0; r < 4; ++r) w[r] = f2bf(acc[mt][nt][r] * sc);
                if (MODE == 2) {
#pragma unroll
                    for (int r = 0; r < 4; ++r)
                        ((u16*)out)[(m0 + r) * N + n] = w[r];
                    *(u16x4*)&((u16*)out2)[n * (long)M + m0] = w;
                } else {  // MODE 3
                    *(u16x4*)&((u16*)out)[n * (long)M + m0] = w;
                }
            }
        }
    }
}

// Fused 7-slab GEMM + mLSTM gate math.
// A = xn [M,K=1024], Wbig [7*1024, K] slabs q,k,v,i,f,o,adj (k pre-scaled).
// Block 64(M) x 64(N); wave w owns N-cols [16w,16w+16) x 64 M x 7 slabs.
// Per K-step: 4 A-reads + 7 B-reads feed 28 MFMAs/wave. Writes ht and
// sadj = sigmoid(x_adj), both bf16 [M,1024].
__global__ __launch_bounds__(256) void gemm_seven(
    const u16* __restrict__ A, const u16* __restrict__ Wbig,
    const float* __restrict__ beff, u16* __restrict__ ht,
    u16* __restrict__ sadj, int M, int K)
{
    __shared__ __align__(16) u16 As[64 * 32];        // 4 KB
    __shared__ __align__(16) u16 Bs[7 * 64 * 32];    // 28 KB

    const int tid  = threadIdx.x;
    const int lane = tid & 63;
    const int wave = tid >> 6;
    const int l15  = lane & 15;
    const int quad = lane >> 4;

    const long bm = (long)blockIdx.y * 64;
    const long bn = (long)blockIdx.x * 64;

    f32x4 acc[7][4] = {};

    const int  r0 = tid >> 2;
    const int  ck = (((tid & 3) ^ ((tid >> 3) & 3)) * 8);
    const u16* ga = A    + (bm + r0) * (long)K + ck;
    const u16* gb = Wbig + (bn + r0) * (long)K + ck;   // slab g at +g*1024*K
    u16* lA = &As[wave * 512];
    u16* lB = &Bs[wave * 512];

    const int q8s = (quad ^ ((l15 >> 1) & 3)) * 8;
    const int brow = (wave * 16 + l15) * 32 + q8s;

    for (int k0 = 0; k0 < K; k0 += 32) {
        GLDS16(ga + k0, lA);
#pragma unroll
        for (int g = 0; g < 7; ++g)
            GLDS16(gb + (long)g * 1024 * K + k0, lB + g * 2048);
        __syncthreads();

        bf16x8 af[4];
#pragma unroll
        for (int t = 0; t < 4; ++t)
            af[t] = *(const bf16x8*)&As[(t * 16 + l15) * 32 + q8s];
#pragma unroll
        for (int g = 0; g < 7; ++g) {
            const bf16x8 bfrag = *(const bf16x8*)&Bs[g * 2048 + brow];
#pragma unroll
            for (int t = 0; t < 4; ++t)
                acc[g][t] = __builtin_amdgcn_mfma_f32_16x16x32_bf16(
                    af[t], bfrag, acc[g][t], 0, 0, 0);
        }
        __syncthreads();
    }

    // C/D layout: col = lane&15, row = quad*4 + reg. One n per lane.
    const long n = bn + wave * 16 + l15;
    const float bqn = beff[n],            bkn = beff[1024 + n];
    const float bvn = beff[2 * 1024 + n], bin = beff[3 * 1024 + n];
    const float bfn = beff[4 * 1024 + n], bon = beff[5 * 1024 + n];
    const float ban = beff[6 * 1024 + n];
#pragma unroll
    for (int t = 0; t < 4; ++t) {
        const long m0 = bm + t * 16 + quad * 4;
#pragma unroll
        for (int r = 0; r < 4; ++r) {
            const float qf = acc[0][t][r] + bqn;
            const float kf = acc[1][t][r] + bkn;   // 1/8 pre-folded
            const float vf = acc[2][t][r] + bvn;
            const float fi = acc[3][t][r] + bin;
            const float ff = acc[4][t][r] + bfn;
            const float osig = sigmoidf(acc[5][t][r] + bon);
            const float xa = acc[6][t][r] + ban;
            const float mx = fmaxf(ff, fi);
            const float fe = __expf(ff - mx);
            const float ct = fe * vf * kf;
            const float h  = osig * (ct * qf) / fmaxf(fabsf(kf * qf), 1.0f);
            ht[(m0 + r) * 1024 + n]   = f2bf(h);
            sadj[(m0 + r) * 1024 + n] = f2bf(sigmoidf(xa));
        }
    }
}

// LayerNorm over 1024 cols, fp32 in -> bf16 out. One 256-thread block per row.
__global__ __launch_bounds__(256) void ln_in_kernel(
    const float* __restrict__ x, const float* __restrict__ g,
    const float* __restrict__ b, u16* __restrict__ xn)
{
    const long row = blockIdx.x;
    const int  tid = threadIdx.x;
    const float4 v = ((const float4*)(x + row * 1024))[tid];
    float s  = v.x + v.y + v.z + v.w;
    float s2 = v.x * v.x + v.y * v.y + v.z * v.z + v.w * v.w;
#pragma unroll
    for (int off = 32; off > 0; off >>= 1) {
        s  += __shfl_down(s, off);
        s2 += __shfl_down(s2, off);
    }
    __shared__ float red[8];
    const int wave = tid >> 6;
    if ((tid & 63) == 0) { red[wave] = s; red[4 + wave] = s2; }
    __syncthreads();
    if (tid == 0) {
        const float S  = red[0] + red[1] + red[2] + red[3];
        const float S2 = red[4] + red[5] + red[6] + red[7];
        const float mu = S * (1.0f / 1024.0f);
        const float var = S2 * (1.0f / 1024.0f) - mu * mu;
        red[0] = mu; red[1] = rsqrtf(var + 1e-3f);
    }
    __syncthreads();
    const float mu = red[0], rstd = red[1];
    const int c = tid * 4;
    u16x4 o;
    o.x = f2bf((v.x - mu) * rstd * g[c + 0] + b[c + 0]);
    o.y = f2bf((v.y - mu) * rstd * g[c + 1] + b[c + 1]);
    o.z = f2bf((v.z - mu) * rstd * g[c + 2] + b[c + 2]);
    o.w = f2bf((v.w - mu) * rstd * g[c + 3] + b[c + 3]);
    *(u16x4*)(xn + row * 1024 + c) = o;
}

// transpose + f32->bf16: W[K,N] -> Wt[N,K]. grid (N/32, K/32)
__global__ __launch_bounds__(256) void convT_kernel(
    const float* __restrict__ W, u16* __restrict__ Wt, int K, int N)
{
    __shared__ float t[32][33];
    const int tx = threadIdx.x & 31;
    const int ty = threadIdx.x >> 5;
    const long bn = (long)blockIdx.x * 32;
    const long bk = (long)blockIdx.y * 32;
#pragma unroll
    for (int j = 0; j < 4; ++j)
        t[ty + j * 8][tx] = W[(bk + ty + j * 8) * N + bn + tx];
    __syncthreads();
#pragma unroll
    for (int j = 0; j < 4; ++j)
        Wt[(bn + ty + j * 8) * K + bk + tx] = f2bf(t[tx][ty + j * 8]);
}

// plain f32 -> bf16 convert (no transpose), 4 elems/thread
__global__ __launch_bounds__(256) void conv_kernel(
    const float* __restrict__ W, u16* __restrict__ Wb)
{
    const long i = ((long)blockIdx.x * 256 + threadIdx.x) * 4;
    const float4 v = *(const float4*)&W[i];
    u16x4 o;
    o.x = f2bf(v.x); o.y = f2bf(v.y); o.z = f2bf(v.z); o.w = f2bf(v.w);
    *(u16x4*)&Wb[i] = o;
}

// b_comb[n] = sum_p b_up[p] * W_adj[p,n] + b_adj[n]   (n < 1024, P=2048)
__global__ __launch_bounds__(256) void bvec_comb_kernel(
    const float* __restrict__ b_up, const float* __restrict__ W_adj,
    const float* __restrict__ b_adj, float* __restrict__ beff6)
{
    const int n = blockIdx.x * 256 + threadIdx.x;
    float s = b_adj[n];
#pragma unroll 8
    for (int p = 0; p < 2048; ++p) s += b_up[p] * W_adj[p * 1024 + n];
    beff6[n] = s;
}

// beff[g*1024+n] = (sum_h b_comb[h] * Wg[h,n] + bg[n]) * (g==1 ? 1/8 : 1)
__global__ __launch_bounds__(256) void bvec_gates_kernel(
    const float* __restrict__ bcomb,
    const float* __restrict__ W0, const float* __restrict__ W1,
    const float* __restrict__ W2, const float* __restrict__ W3,
    const float* __restrict__ W4, const float* __restrict__ W5,
    const float* __restrict__ c0, const float* __restrict__ c1,
    const float* __restrict__ c2, const float* __restrict__ c3,
    const float* __restrict__ c4, const float* __restrict__ c5,
    float* __restrict__ beff)
{
    const int g = blockIdx.y;
    const int n = blockIdx.x * 256 + threadIdx.x;
    const float* W; const float* bb;
    switch (g) {
        case 0: W = W0; bb = c0; break;
        case 1: W = W1; bb = c1; break;
        case 2: W = W2; bb = c2; break;
        case 3: W = W3; bb = c3; break;
        case 4: W = W4; bb = c4; break;
        default: W = W5; bb = c5; break;
    }
    float s = bb[n];
#pragma unroll 8
    for (int h = 0; h < 1024; ++h) s += bcomb[h] * W[h * 1024 + n];
    if (g == 1) s *= 0.125f;
    beff[g * 1024 + n] = s;
}

// LN2 over ht rows, times precomputed sadj. y may alias ht (same-thread r/w).
__global__ __launch_bounds__(256) void ln2_kernel(
    const u16* __restrict__ ht, const u16* __restrict__ sadj,
    const float* __restrict__ g2, const float* __restrict__ b2,
    u16* __restrict__ y)
{
    const long base = (long)blockIdx.x * 1024;
    const int  tid = threadIdx.x;
    const int  c = tid * 4;
    const u16x4 hv = *(const u16x4*)&ht[base + c];
    const u16x4 sv = *(const u16x4*)&sadj[base + c];

    float h[4];
    float s = 0.0f, s2 = 0.0f;
#pragma unroll
    for (int j = 0; j < 4; ++j) {
        h[j] = bf2f(hv[j]);
        s += h[j]; s2 += h[j] * h[j];
    }
#pragma unroll
    for (int off = 32; off > 0; off >>= 1) {
        s  += __shfl_down(s, off);
        s2 += __shfl_down(s2, off);
    }
    __shared__ float red[8];
    const int wave = tid >> 6;
    if ((tid & 63) == 0) { red[wave] = s; red[4 + wave] = s2; }
    __syncthreads();
    if (tid == 0) {
        const float S  = red[0] + red[1] + red[2] + red[3];
        const float S2 = red[4] + red[5] + red[6] + red[7];
        const float mu = S * (1.0f / 1024.0f);
        const float var = S2 * (1.0f / 1024.0f) - mu * mu;
        red[0] = mu; red[1] = rsqrtf(var + 1e-3f);
    }
    __syncthreads();
    const float mu = red[0], rstd = red[1];
    u16x4 o;
#pragma unroll
    for (int j = 0; j < 4; ++j)
        o[j] = f2bf(((h[j] - mu) * rstd * g2[c + j] + b2[c + j]) * bf2f(sv[j]));
    *(u16x4*)&y[base + c] = o;
}

extern "C" void kernel_launch(void* const* d_in, const int* in_sizes, int n_in,
                              void* d_out, int out_size, void* d_ws, size_t ws_size,
                              hipStream_t stream)
{
    const float* x    = (const float*)d_in[0];
    const float* g1   = (const float*)d_in[1];
    const float* b1   = (const float*)d_in[2];
    const float* Wup  = (const float*)d_in[3];
    const float* bup  = (const float*)d_in[4];
    const float* Wadj = (const float*)d_in[5];
    const float* badj = (const float*)d_in[6];
    const float* Wq = (const float*)d_in[7];   const float* bq = (const float*)d_in[8];
    const float* Wk = (const float*)d_in[9];   const float* bk = (const float*)d_in[10];
    const float* Wv = (const float*)d_in[11];  const float* bv = (const float*)d_in[12];
    const float* Wi = (const float*)d_in[13];  const float* bi = (const float*)d_in[14];
    const float* Wf = (const float*)d_in[15];  const float* bf = (const float*)d_in[16];
    const float* Wo = (const float*)d_in[17];  const float* bo = (const float*)d_in[18];
    const float* g2 = (const float*)d_in[19];  const float* b2 = (const float*)d_in[20];
    const float* Wdn = (const float*)d_in[21]; const float* bdn = (const float*)d_in[22];

    const int M = 8 * 2048;     // 16384 tokens
    const int D = 1024, P = 2048, H = 1024;

    char* ws = (char*)d_ws;
    const size_t MB = 1024 * 1024;
    u16*   xn     = (u16*)(ws + 0);
    u16*   htb    = (u16*)(ws + 32 * MB);
    u16*   sadjb  = (u16*)(ws + 64 * MB);
    u16*   yb     = htb;                       // ln2 same-thread r/w alias
    u16*   Wbig   = (u16*)(ws + 96 * MB);      // [7*1024,1024] 14MB
    u16*   Wcomb  = (u16*)(ws + 110 * MB);     // [1024,1024] bf16 normal
    u16*   WupB   = (u16*)(ws + 112 * MB);     // [1024,2048] bf16 (no T)
    u16*   WadjT  = (u16*)(ws + 116 * MB);     // [1024,2048]
    u16*   WgTcat = (u16*)(ws + 120 * MB);     // [6*1024,1024] 12MB
    u16*   WdnT   = (u16*)(ws + 132 * MB);     // [1024,1024]
    float* beff   = (float*)(ws + 134 * MB);   // [7*1024] f32

    // 1) LN1
    ln_in_kernel<<<M, 256, 0, stream>>>(x, g1, b1, xn);

    // 2) weight conversions
    conv_kernel<<<(D * P) / (4 * 256), 256, 0, stream>>>(Wup, WupB);
    convT_kernel<<<dim3(H / 32, P / 32), 256, 0, stream>>>(Wadj, WadjT, P, H);
    convT_kernel<<<dim3(H / 32, H / 32), 256, 0, stream>>>(Wq, WgTcat + 0 * H * H, H, H);
    convT_kernel<<<dim3(H / 32, H / 32), 256, 0, stream>>>(Wk, WgTcat + 1 * H * H, H, H);
    convT_kernel<<<dim3(H / 32, H / 32), 256, 0, stream>>>(Wv, WgTcat + 2 * H * H, H, H);
    convT_kernel<<<dim3(H / 32, H / 32), 256, 0, stream>>>(Wi, WgTcat + 3 * H * H, H, H);
    convT_kernel<<<dim3(H / 32, H / 32), 256, 0, stream>>>(Wf, WgTcat + 4 * H * H, H, H);
    convT_kernel<<<dim3(H / 32, H / 32), 256, 0, stream>>>(Wo, WgTcat + 5 * H * H, H, H);
    convT_kernel<<<dim3(D / 32, H / 32), 256, 0, stream>>>(Wdn, WdnT, H, D);

    // 3) effective biases
    bvec_comb_kernel<<<4, 256, 0, stream>>>(bup, Wadj, badj, beff + 6 * 1024);
    bvec_gates_kernel<<<dim3(4, 6), 256, 0, stream>>>(
        beff + 6 * 1024, Wq, Wk, Wv, Wi, Wf, Wo, bq, bk, bv, bi, bf, bo, beff);

    // 4) W_comb = Wup @ Wadj -> normal (Wcomb) + transposed (Wbig slab 6)
    gemm_bt<2><<<dim3(H / BN, D / BM), 256, 0, stream>>>(
        WupB, WadjT, nullptr, nullptr, Wcomb, Wbig + 6 * H * D, D, H, P, 1.0f);

    // 5) Weff[g] = W_comb @ Wg -> transposed into Wbig slabs 0..5 (k slab /8)
    gemm_bt<3><<<dim3(6 * H / BN, D / BM), 256, 0, stream>>>(
        Wcomb, WgTcat, nullptr, nullptr, Wbig, nullptr, D, 6 * H, H, 1.0f);

    // 6) fused 7-slab GEMM + gate math -> ht, sadj
    gemm_seven<<<dim3(H / 64, M / 64), 256, 0, stream>>>(
        xn, Wbig, beff, htb, sadjb, M, D);

    // 7) LN2 * sadj -> y
    ln2_kernel<<<M, 256, 0, stream>>>(htb, sadjb, g2, b2, yb);

    // 8) down-proj + bias + residual, fp32 out
    gemm_bt<1><<<dim3(D / BN, M / BM), 256, 0, stream>>>(
        yb, WdnT, bdn, x, (float*)d_out, nullptr, M, D, H, 1.0f);
}